// Round 10
// baseline (100.655 us; speedup 1.0000x reference)
//
#include <hip/hip_runtime.h>
#include <hip/hip_bf16.h>

#define NB 4
#define SEQ 2048
#define DMODEL 1024
#define DKEY 128

using f32x4  = __attribute__((ext_vector_type(4))) float;
using bf16x8 = __attribute__((ext_vector_type(8))) short;           // 8 bf16 (4 VGPRs)
using u16x4  = __attribute__((ext_vector_type(4))) unsigned short;
using u16x8  = __attribute__((ext_vector_type(8))) unsigned short;

__device__ __forceinline__ unsigned short f2bf(float f) {
  __hip_bfloat16 h = __float2bfloat16(f);
  return __builtin_bit_cast(unsigned short, h);
}
__device__ __forceinline__ bf16x8 pack8(float4 lo, float4 hi) {
  u16x8 p = { f2bf(lo.x), f2bf(lo.y), f2bf(lo.z), f2bf(lo.w),
              f2bf(hi.x), f2bf(hi.y), f2bf(hi.z), f2bf(hi.w) };
  return __builtin_bit_cast(bf16x8, p);
}

// ---------------------------------------------------------------------------
// W pre-convert: Wq/Wk/Wv fp32 [128][1024] -> bf16 Wb[3][128][1024].
// 192 blocks x 256 thr, 8 elems/thread.
// ---------------------------------------------------------------------------
__global__ __launch_bounds__(256) void wconv_kernel(
    const float* __restrict__ Wq, const float* __restrict__ Wk,
    const float* __restrict__ Wv, unsigned short* __restrict__ Wb)
{
  int id = blockIdx.x * 256 + threadIdx.x;            // 0..49151
  const float* src = (id < 16384) ? Wq : (id < 32768) ? Wk : Wv;
  int off = (id & 16383) * 8;
  float4 a = *reinterpret_cast<const float4*>(&src[off]);
  float4 b = *reinterpret_cast<const float4*>(&src[off + 4]);
  u16x8 p = { f2bf(a.x), f2bf(a.y), f2bf(a.z), f2bf(a.w),
              f2bf(b.x), f2bf(b.y), f2bf(b.z), f2bf(b.w) };
  *reinterpret_cast<u16x8*>(&Wb[(size_t)(id >> 14) * 131072 + off]) = p;
}

// ---------------------------------------------------------------------------
// Projection, barrier-free streaming: Y[m][n] = sum_d X[m][d] * W[n][d].
// X fp32 [8192][1024]; W pre-converted bf16 [128][1024] (L2-resident).
// Grid 128 x 3 (z: 0=Q, 1=K, 2=V^T). Block = 64 rows; wave = 32 rows x 64
// cols (wm = row half, wn = col half). A-fragments DIRECT from global fp32
// (lane (lr,hi) reads X[row=..+lr][ks*32+hi*8], 2 float4 — each row's 128B
// line fully consumed within one instr); B-fragments direct from bf16 W.
// Unroll-2 two-ring explicit prefetch, NO barriers in the K-loop -> waves
// independent, deep VMEM queue. z=2 transposes via LDS once per block.
// MFMA conventions (m89/m92 HW-verified):
//   A: lane holds A[lane&15][(lane>>4)*8+j]   B: B[(lane>>4)*8+j][lane&15]
//   C/D: col = lane&15, row = (lane>>4)*4 + reg
// ---------------------------------------------------------------------------
__global__ __launch_bounds__(256, 1) void proj_kernel(
    const float* __restrict__ Xq, const float* __restrict__ Xk, const float* __restrict__ Xv,
    const unsigned short* __restrict__ Wb,
    unsigned short* __restrict__ Yq, unsigned short* __restrict__ Yk,
    unsigned short* __restrict__ Vt)
{
  const int z = blockIdx.z;
  const float* X = (z == 0) ? Xq : (z == 1) ? Xk : Xv;
  const unsigned short* W = Wb + (size_t)z * 131072;

  __shared__ alignas(16) unsigned short Tl[128][72];   // z=2 transpose buffer

  const int t    = threadIdx.x;
  const int lane = t & 63;
  const int w    = t >> 6;
  const int wm   = w >> 1;       // row half (32 rows)
  const int wn   = w & 1;        // col half (64 cols)
  const int lr   = lane & 15;
  const int hi   = lane >> 4;
  const int lk   = hi * 8;
  const int rbase = hi * 4;
  const long m0  = (long)blockIdx.x * 64;

  const float* pA0 = X + (m0 + wm * 32 + 0  + lr) * (long)DMODEL + lk;
  const float* pA1 = X + (m0 + wm * 32 + 16 + lr) * (long)DMODEL + lk;
  const unsigned short* pB0 = W + (wn * 64 + 0  + lr) * DMODEL + lk;
  const unsigned short* pB1 = W + (wn * 64 + 16 + lr) * DMODEL + lk;
  const unsigned short* pB2 = W + (wn * 64 + 32 + lr) * DMODEL + lk;
  const unsigned short* pB3 = W + (wn * 64 + 48 + lr) * DMODEL + lk;

  f32x4 acc[2][4];
  const f32x4 zero = {0.f, 0.f, 0.f, 0.f};
#pragma unroll
  for (int m = 0; m < 2; ++m)
#pragma unroll
    for (int n = 0; n < 4; ++n) acc[m][n] = zero;

  float4 xa[2][4];
  bf16x8 wf[2][4];

#define PJ_LOAD(rg, ks) do {                                                  \
    xa[rg][0] = *reinterpret_cast<const float4*>(pA0 + (ks) * 32);            \
    xa[rg][1] = *reinterpret_cast<const float4*>(pA0 + (ks) * 32 + 4);        \
    xa[rg][2] = *reinterpret_cast<const float4*>(pA1 + (ks) * 32);            \
    xa[rg][3] = *reinterpret_cast<const float4*>(pA1 + (ks) * 32 + 4);        \
    wf[rg][0] = *reinterpret_cast<const bf16x8*>(pB0 + (ks) * 32);            \
    wf[rg][1] = *reinterpret_cast<const bf16x8*>(pB1 + (ks) * 32);            \
    wf[rg][2] = *reinterpret_cast<const bf16x8*>(pB2 + (ks) * 32);            \
    wf[rg][3] = *reinterpret_cast<const bf16x8*>(pB3 + (ks) * 32);            \
  } while (0)

#define PJ_COMP(rg) do {                                                      \
    bf16x8 a0 = pack8(xa[rg][0], xa[rg][1]);                                  \
    bf16x8 a1 = pack8(xa[rg][2], xa[rg][3]);                                  \
    _Pragma("unroll")                                                         \
    for (int n = 0; n < 4; ++n) {                                             \
      acc[0][n] = __builtin_amdgcn_mfma_f32_16x16x32_bf16(a0, wf[rg][n], acc[0][n], 0, 0, 0); \
      acc[1][n] = __builtin_amdgcn_mfma_f32_16x16x32_bf16(a1, wf[rg][n], acc[1][n], 0, 0, 0); \
    }                                                                         \
  } while (0)

  PJ_LOAD(0, 0);
  for (int ks = 0; ks < 32; ks += 2) {
    PJ_LOAD(1, ks + 1);
    PJ_COMP(0);
    if (ks + 2 < 32) PJ_LOAD(0, ks + 2);
    PJ_COMP(1);
  }
#undef PJ_LOAD
#undef PJ_COMP

  if (z != 2) {
    unsigned short* Y = (z == 0) ? Yq : Yk;
#pragma unroll
    for (int m = 0; m < 2; ++m)
#pragma unroll
      for (int n = 0; n < 4; ++n)
#pragma unroll
        for (int r = 0; r < 4; ++r) {
          long row = m0 + wm * 32 + m * 16 + rbase + r;
          Y[row * DKEY + wn * 64 + n * 16 + lr] = f2bf(acc[m][n][r]);
        }
  } else {
    // transpose epilogue: acc (64 s-rows x 128 d) -> Vt[b][d][s]
#pragma unroll
    for (int m = 0; m < 2; ++m)
#pragma unroll
      for (int n = 0; n < 4; ++n)
#pragma unroll
        for (int r = 0; r < 4; ++r)
          Tl[wn * 64 + n * 16 + lr][wm * 32 + m * 16 + rbase + r] = f2bf(acc[m][n][r]);
    __syncthreads();
    const int bb = (int)(m0 >> 11);      // 2048 rows per batch
    const int s0 = (int)(m0 & 2047);
#pragma unroll
    for (int i = 0; i < 4; ++i) {
      int id = t + 256 * i;              // 1024 chunks of 8
      int dr = id >> 3;
      int c8 = (id & 7) << 3;
      u16x8 v = *reinterpret_cast<const u16x8*>(&Tl[dr][c8]);
      *reinterpret_cast<u16x8*>(&Vt[((size_t)bb * DKEY + dr) * SEQ + s0 + c8]) = v;
    }
  }
}

// ---------------------------------------------------------------------------
// Causal flash attention (round-9 version, measured ~14 us): 256 blocks
// (1/CU) = 64 q-tiles(32 rows) x 4 batches. 8 waves = 4 KV-split groups x 2;
// group g stages K[64][128] + Vt[128][64] with coalesced u16x8 loads into
// slot-XOR-swizzled LDS, 2 barriers/step. In-register softmax, per-wave P,
// 4-way flash merge over K-LDS alias.
// ---------------------------------------------------------------------------
__global__ __launch_bounds__(512, 2) void attn_kernel(
    const unsigned short* __restrict__ Q,
    const unsigned short* __restrict__ K,
    const unsigned short* __restrict__ Vt,
    float* __restrict__ O)
{
  const int  L    = blockIdx.x;
  const int  b    = (L & 7) >> 1;                     // batch -> XCD pair
  const int  qt   = 63 - (((L >> 3) << 1) | (L & 1)); // long blocks first
  const int  q0   = qt * 32;
  const long base = (long)b * SEQ;
  const int  nt   = (q0 >> 6) + 1;                    // 64-wide KV tiles
  const int  nsteps = (nt + 3) >> 2;

  __shared__ alignas(16) unsigned short Kl[4][64][128];   // 64 KB (xor-swizzled)
  __shared__ alignas(16) unsigned short Vl[4][128][64];   // 64 KB (xor-swizzled)
  __shared__ alignas(16) unsigned short Plds[8][16][72];  // per-wave P (+8 pad)
  __shared__ float Sm[4][32], Sl[4][32];

  const int t     = threadIdx.x;
  const int lane  = t & 63;
  const int w     = t >> 6;      // 0..7
  const int g     = w >> 1;      // KV group 0..3
  const int wq    = w & 1;       // 16-row half within group
  const int lr    = lane & 15;
  const int hi    = lane >> 4;
  const int lk    = hi * 8;
  const int rbase = hi * 4;

  bf16x8 qa[4];
  {
    const long qrow = (base + q0 + wq * 16 + lr) * (long)DKEY;
#pragma unroll
    for (int dk = 0; dk < 4; ++dk)
      qa[dk] = *reinterpret_cast<const bf16x8*>(&Q[qrow + dk * 32 + lk]);
  }

  const f32x4 zero = {0.f, 0.f, 0.f, 0.f};
  f32x4 oacc[8];
#pragma unroll
  for (int n = 0; n < 8; ++n) oacc[n] = zero;
  float m_run[4], l_run[4];
#pragma unroll
  for (int r = 0; r < 4; ++r) { m_run[r] = -1e30f; l_run[r] = 0.0f; }

  const float sc = 0.08838834764831845f;  // 1/sqrt(128)
  const unsigned short* VtB = Vt + (size_t)b * DKEY * SEQ;

  for (int st = 0; st < nsteps; ++st) {
    const int kt  = st * 4 + g;
    const bool act = kt < nt;
    const int kv0 = kt * 64;

    if (act) {
      const unsigned short* Kp = K + (base + kv0) * (long)DKEY;
#pragma unroll
      for (int it = 0; it < 8; ++it) {
        int c = it * 128 + wq * 64 + lane;
        int row = c >> 4, sl = (c & 15) ^ (row & 7);
        *reinterpret_cast<u16x8*>(&Kl[g][row][sl * 8]) =
            *reinterpret_cast<const u16x8*>(&Kp[(size_t)c * 8]);
      }
#pragma unroll
      for (int it = 0; it < 8; ++it) {
        int c = it * 128 + wq * 64 + lane;
        int d = c >> 3, sl = c & 7, slp = sl ^ (d & 7);
        *reinterpret_cast<u16x8*>(&Vl[g][d][slp * 8]) =
            *reinterpret_cast<const u16x8*>(&VtB[(size_t)d * SEQ + kv0 + sl * 8]);
      }
    }
    __syncthreads();

    if (act) {
      f32x4 s[4];
#pragma unroll
      for (int kc = 0; kc < 4; ++kc) {
        s[kc] = zero;
#pragma unroll
        for (int dk = 0; dk < 4; ++dk) {
          bf16x8 kb = *reinterpret_cast<const bf16x8*>(
              &Kl[g][kc * 16 + lr][((dk * 4 + hi) ^ (lr & 7)) * 8]);
          s[kc] = __builtin_amdgcn_mfma_f32_16x16x32_bf16(qa[dk], kb, s[kc], 0, 0, 0);
        }
      }

      const bool dmask = (kt == nt - 1);
      float x[4][4];
#pragma unroll
      for (int kc = 0; kc < 4; ++kc)
#pragma unroll
        for (int r = 0; r < 4; ++r) {
          float xv = s[kc][r] * sc;
          if (dmask) {
            int col  = kv0 + kc * 16 + lr;
            int rowq = q0 + wq * 16 + rbase + r;
            if (col > rowq) xv = -1e30f;
          }
          x[kc][r] = xv;
        }

#pragma unroll
      for (int r = 0; r < 4; ++r) {
        float tm = fmaxf(fmaxf(x[0][r], x[1][r]), fmaxf(x[2][r], x[3][r]));
        tm = fmaxf(tm, __shfl_xor(tm, 1));
        tm = fmaxf(tm, __shfl_xor(tm, 2));
        tm = fmaxf(tm, __shfl_xor(tm, 4));
        tm = fmaxf(tm, __shfl_xor(tm, 8));
        float mnew = fmaxf(m_run[r], tm);
        float scl  = __expf(m_run[r] - mnew);
        m_run[r] = mnew;
        float ps = 0.0f;
#pragma unroll
        for (int kc = 0; kc < 4; ++kc) {
          float pp = __expf(x[kc][r] - mnew);
          ps += pp;
          Plds[w][rbase + r][kc * 16 + lr] = f2bf(pp);
        }
        ps += __shfl_xor(ps, 1);
        ps += __shfl_xor(ps, 2);
        ps += __shfl_xor(ps, 4);
        ps += __shfl_xor(ps, 8);
        l_run[r] = l_run[r] * scl + ps;
#pragma unroll
        for (int n = 0; n < 8; ++n) oacc[n][r] *= scl;
      }

#pragma unroll
      for (int kk = 0; kk < 2; ++kk) {
        bf16x8 pa = *reinterpret_cast<const bf16x8*>(&Plds[w][lr][kk * 32 + lk]);
#pragma unroll
        for (int n = 0; n < 8; ++n) {
          bf16x8 vb = *reinterpret_cast<const bf16x8*>(
              &Vl[g][n * 16 + lr][((kk * 4 + hi) ^ (lr & 7)) * 8]);
          oacc[n] = __builtin_amdgcn_mfma_f32_16x16x32_bf16(pa, vb, oacc[n], 0, 0, 0);
        }
      }
    }
    __syncthreads();
  }

  float* Om = reinterpret_cast<float*>(&Kl[0][0][0]);   // [4][32][128] alias
#pragma unroll
  for (int n = 0; n < 8; ++n)
#pragma unroll
    for (int r = 0; r < 4; ++r)
      Om[(g * 32 + wq * 16 + rbase + r) * 128 + n * 16 + lr] = oacc[n][r];
  if (lr == 0) {
#pragma unroll
    for (int r = 0; r < 4; ++r) {
      Sm[g][wq * 16 + rbase + r] = m_run[r];
      Sl[g][wq * 16 + rbase + r] = l_run[r];
    }
  }
  __syncthreads();

  const int row = t >> 4;          // 0..31
  const int c0  = (t & 15) * 8;    // 0..120
  float mM = fmaxf(fmaxf(Sm[0][row], Sm[1][row]), fmaxf(Sm[2][row], Sm[3][row]));
  float wts[4], lsum = 0.0f;
#pragma unroll
  for (int gv = 0; gv < 4; ++gv) {
    wts[gv] = __expf(Sm[gv][row] - mM);
    lsum += wts[gv] * Sl[gv][row];
  }
  const float linv = 1.0f / lsum;
  f32x4 o0 = zero, o1 = zero;
#pragma unroll
  for (int gv = 0; gv < 4; ++gv) {
    const float* src = &Om[(gv * 32 + row) * 128 + c0];
    f32x4 a0 = *reinterpret_cast<const f32x4*>(src);
    f32x4 a1 = *reinterpret_cast<const f32x4*>(src + 4);
    const float wt = wts[gv];
#pragma unroll
    for (int j = 0; j < 4; ++j) { o0[j] += wt * a0[j]; o1[j] += wt * a1[j]; }
  }
#pragma unroll
  for (int j = 0; j < 4; ++j) { o0[j] *= linv; o1[j] *= linv; }
  float* op = &O[(base + q0 + row) * (long)DKEY + c0];
  *reinterpret_cast<f32x4*>(op)     = o0;
  *reinterpret_cast<f32x4*>(op + 4) = o1;
}

extern "C" void kernel_launch(void* const* d_in, const int* in_sizes, int n_in,
                              void* d_out, int out_size, void* d_ws, size_t ws_size,
                              hipStream_t stream) {
  const float* Xq = (const float*)d_in[0];
  const float* Xk = (const float*)d_in[1];
  const float* Xv = (const float*)d_in[2];
  // d_in[3] = mask: tril by construction; causality handled analytically.
  const float* Wq = (const float*)d_in[4];
  const float* Wk = (const float*)d_in[5];
  const float* Wv = (const float*)d_in[6];

  // ws layout: Q (2MB), K (2MB), V^T (2MB) bf16. ws >= 6MB (round-1 evidence).
  unsigned short* qp  = (unsigned short*)d_ws;
  unsigned short* kp  = qp + (size_t)NB * SEQ * DKEY;
  unsigned short* vtp = kp + (size_t)NB * SEQ * DKEY;
  // W-bf16 (0.75MB) lives in d_out: written by wconv, read only by proj,
  // then fully overwritten by attn's O-stores (stream-ordered => safe,
  // deterministic across graph replays).
  unsigned short* wbp = (unsigned short*)d_out;

  hipLaunchKernelGGL(wconv_kernel, dim3(192), dim3(256), 0, stream,
                     Wq, Wk, Wv, wbp);
  dim3 g1(SEQ * NB / 64, 1, 3);   // 128 x 3
  hipLaunchKernelGGL(proj_kernel, g1, dim3(256), 0, stream,
                     Xq, Xk, Xv, wbp, qp, kp, vtp);
  hipLaunchKernelGGL(attn_kernel, dim3(256), dim3(512), 0, stream,
                     qp, kp, vtp, (float*)d_out);
}

// Round 11
// 66.543 us; speedup vs baseline: 1.5126x; 1.5126x over previous
//
#include <hip/hip_runtime.h>
#include <hip/hip_bf16.h>

#define NB 4
#define SEQ 2048
#define DMODEL 1024
#define DKEY 128

using f32x4  = __attribute__((ext_vector_type(4))) float;
using bf16x8 = __attribute__((ext_vector_type(8))) short;           // 8 bf16 (4 VGPRs)
using u16x4  = __attribute__((ext_vector_type(4))) unsigned short;
using u16x8  = __attribute__((ext_vector_type(8))) unsigned short;

__device__ __forceinline__ unsigned short f2bf(float f) {
  __hip_bfloat16 h = __float2bfloat16(f);
  return __builtin_bit_cast(unsigned short, h);
}
__device__ __forceinline__ bf16x8 pack8(f32x4 lo, f32x4 hi) {
  u16x8 p = { f2bf(lo[0]), f2bf(lo[1]), f2bf(lo[2]), f2bf(lo[3]),
              f2bf(hi[0]), f2bf(hi[1]), f2bf(hi[2]), f2bf(hi[3]) };
  return __builtin_bit_cast(bf16x8, p);
}
// async 16B global->LDS (unsinkable by the compiler; vmcnt-counted)
__device__ __forceinline__ void gload16(const void* g, void* l) {
  __builtin_amdgcn_global_load_lds(
      (const __attribute__((address_space(1))) void*)g,
      (__attribute__((address_space(3))) void*)l, 16, 0, 0);
}

// ---------------------------------------------------------------------------
// W pre-convert: Wq/Wk/Wv fp32 [128][1024] -> bf16 Wb[3][128][1024].
// ---------------------------------------------------------------------------
__global__ __launch_bounds__(256) void wconv_kernel(
    const float* __restrict__ Wq, const float* __restrict__ Wk,
    const float* __restrict__ Wv, unsigned short* __restrict__ Wb)
{
  int id = blockIdx.x * 256 + threadIdx.x;            // 0..49151
  const float* src = (id < 16384) ? Wq : (id < 32768) ? Wk : Wv;
  int off = (id & 16383) * 8;
  float4 a = *reinterpret_cast<const float4*>(&src[off]);
  float4 b = *reinterpret_cast<const float4*>(&src[off + 4]);
  u16x8 p = { f2bf(a.x), f2bf(a.y), f2bf(a.z), f2bf(a.w),
              f2bf(b.x), f2bf(b.y), f2bf(b.z), f2bf(b.w) };
  *reinterpret_cast<u16x8*>(&Wb[(size_t)(id >> 14) * 131072 + off]) = p;
}

// ---------------------------------------------------------------------------
// Projection, async 3-buffer pipeline (m97/T4 style):
//   Y[m][n] = sum_d X[m][d] * W[n][d]
// X fp32 [8192][1024] staged via global_load_lds (fp32 in LDS, cvt on read);
// W bf16 [128][1024] (pre-converted) staged via global_load_lds.
// BM=64 (grid 128 x 3), 4 waves x (16 rows x 128 cols), BK=32.
// 3 LDS buffers, issue 2 tiles ahead, counted s_waitcnt vmcnt(4) (never 0
// mid-loop) + ONE raw s_barrier per step.  Source-side XOR swizzle
// (granule ^ row&7 for X / row&3 for W) + matching swizzled ds_reads.
// z=0 Q, z=1 K row-major; z=2 V^T via LDS transpose epilogue.
// MFMA conventions (m89/m92 HW-verified):
//   A: lane holds A[lane&15][(lane>>4)*8+j]   B: B[(lane>>4)*8+j][lane&15]
//   C/D: col = lane&15, row = (lane>>4)*4 + reg
// ---------------------------------------------------------------------------
__global__ __launch_bounds__(256, 2) void proj_kernel(
    const float* __restrict__ Xq, const float* __restrict__ Xk, const float* __restrict__ Xv,
    const unsigned short* __restrict__ Wb,
    unsigned short* __restrict__ Yq, unsigned short* __restrict__ Yk,
    unsigned short* __restrict__ Vt)
{
  const int z = blockIdx.z;
  const float* X = (z == 0) ? Xq : (z == 1) ? Xk : Xv;
  const unsigned short* W = Wb + (size_t)z * 131072;

  __shared__ alignas(16) float          XL[3][64 * 32];    // 3 x 8 KB fp32
  __shared__ alignas(16) unsigned short WL[3][128 * 32];   // 3 x 8 KB bf16
  __shared__ alignas(16) unsigned short Tl[128][72];       // z=2 transpose

  const int t     = threadIdx.x;
  const int lane  = t & 63;
  const int w     = t >> 6;
  const int lr    = lane & 15;
  const int hi    = lane >> 4;
  const int rbase = hi * 4;
  const long m0   = (long)blockIdx.x * 64;

  // per-thread staging geometry (granule = 16 B)
  // X: granule G = i*256+t -> row=G>>3, g=G&7, swizzled col float = (g^(row&7))*4
  // W: granule G = i*256+t -> row=G>>2, g=G&3, swizzled col u16  = (g^(row&3))*8
  const int xg_row[2] = { (0 * 256 + t) >> 3, (1 * 256 + t) >> 3 };
  const int xg_col[2] = { ((((0 * 256 + t) & 7) ^ (xg_row[0] & 7)) << 2),
                          ((((1 * 256 + t) & 7) ^ (xg_row[1] & 7)) << 2) };
  const int wg_row[2] = { (0 * 256 + t) >> 2, (1 * 256 + t) >> 2 };
  const int wg_col[2] = { ((((0 * 256 + t) & 3) ^ (wg_row[0] & 3)) << 3),
                          ((((1 * 256 + t) & 3) ^ (wg_row[1] & 3)) << 3) };

#define PJ_ISSUE(ks) do {                                                     \
    const int _b = (ks) % 3;                                                  \
    _Pragma("unroll")                                                         \
    for (int i = 0; i < 2; ++i) {                                             \
      gload16(&X[(m0 + xg_row[i]) * (long)DMODEL + (ks) * 32 + xg_col[i]],    \
              &XL[_b][(i * 256 + w * 64) * 4]);                               \
      gload16(&W[(size_t)wg_row[i] * DMODEL + (ks) * 32 + wg_col[i]],         \
              &WL[_b][(i * 256 + w * 64) * 8]);                               \
    }                                                                         \
  } while (0)

  f32x4 acc[8];
  const f32x4 zero = {0.f, 0.f, 0.f, 0.f};
#pragma unroll
  for (int n = 0; n < 8; ++n) acc[n] = zero;

  PJ_ISSUE(0);
  PJ_ISSUE(1);

  const int arow = w * 16 + lr;            // A row; arow&7 == lr&7
  for (int ks = 0; ks < 32; ++ks) {
    // own-wave tile-ks loads complete (outstanding = {ks, ks+1} x4)
    if (ks < 31) asm volatile("s_waitcnt vmcnt(4)" ::: "memory");
    else         asm volatile("s_waitcnt vmcnt(0)" ::: "memory");
    __builtin_amdgcn_s_barrier();
    if (ks + 2 < 32) PJ_ISSUE(ks + 2);

    const int buf = ks % 3;
    const float* xrow = &XL[buf][arow * 32];
    f32x4 xlo = *reinterpret_cast<const f32x4*>(xrow + (((hi * 2)     ^ (lr & 7)) << 2));
    f32x4 xhi = *reinterpret_cast<const f32x4*>(xrow + (((hi * 2 + 1) ^ (lr & 7)) << 2));
    bf16x8 a = pack8(xlo, xhi);
#pragma unroll
    for (int n = 0; n < 8; ++n) {
      const int wrow = n * 16 + lr;
      bf16x8 b = *reinterpret_cast<const bf16x8*>(
          &WL[buf][wrow * 32 + ((hi ^ (wrow & 3)) << 3)]);
      acc[n] = __builtin_amdgcn_mfma_f32_16x16x32_bf16(a, b, acc[n], 0, 0, 0);
    }
  }
#undef PJ_ISSUE

  if (z != 2) {
    unsigned short* Y = (z == 0) ? Yq : Yk;
#pragma unroll
    for (int n = 0; n < 8; ++n)
#pragma unroll
      for (int r = 0; r < 4; ++r) {
        long row = m0 + w * 16 + rbase + r;
        Y[row * DKEY + n * 16 + lr] = f2bf(acc[n][r]);
      }
  } else {
    // transpose epilogue: acc (64 s-rows x 128 d) -> Vt[b][d][s]
    __syncthreads();   // all LDS buffer traffic done before Tl reuse pattern
#pragma unroll
    for (int n = 0; n < 8; ++n)
#pragma unroll
      for (int r = 0; r < 4; ++r)
        Tl[n * 16 + lr][w * 16 + rbase + r] = f2bf(acc[n][r]);
    __syncthreads();
    const int bb = (int)(m0 >> 11);      // 2048 rows per batch
    const int s0 = (int)(m0 & 2047);
#pragma unroll
    for (int i = 0; i < 4; ++i) {
      int id = t + 256 * i;              // 1024 chunks of 8
      int dr = id >> 3;
      int c8 = (id & 7) << 3;
      u16x8 v = *reinterpret_cast<const u16x8*>(&Tl[dr][c8]);
      *reinterpret_cast<u16x8*>(&Vt[((size_t)bb * DKEY + dr) * SEQ + s0 + c8]) = v;
    }
  }
}

// ---------------------------------------------------------------------------
// Causal flash attention (round-9 version, UNCHANGED): 256 blocks (1/CU) =
// 64 q-tiles(32 rows) x 4 batches. 8 waves = 4 KV-split groups x 2; group g
// stages K[64][128] + Vt[128][64] with coalesced u16x8 loads into
// slot-XOR-swizzled LDS, 2 barriers/step. In-register softmax, per-wave P,
// 4-way flash merge over K-LDS alias.
// ---------------------------------------------------------------------------
__global__ __launch_bounds__(512, 2) void attn_kernel(
    const unsigned short* __restrict__ Q,
    const unsigned short* __restrict__ K,
    const unsigned short* __restrict__ Vt,
    float* __restrict__ O)
{
  const int  L    = blockIdx.x;
  const int  b    = (L & 7) >> 1;                     // batch -> XCD pair
  const int  qt   = 63 - (((L >> 3) << 1) | (L & 1)); // long blocks first
  const int  q0   = qt * 32;
  const long base = (long)b * SEQ;
  const int  nt   = (q0 >> 6) + 1;                    // 64-wide KV tiles
  const int  nsteps = (nt + 3) >> 2;

  __shared__ alignas(16) unsigned short Kl[4][64][128];   // 64 KB (xor-swizzled)
  __shared__ alignas(16) unsigned short Vl[4][128][64];   // 64 KB (xor-swizzled)
  __shared__ alignas(16) unsigned short Plds[8][16][72];  // per-wave P (+8 pad)
  __shared__ float Sm[4][32], Sl[4][32];

  const int t     = threadIdx.x;
  const int lane  = t & 63;
  const int w     = t >> 6;      // 0..7
  const int g     = w >> 1;      // KV group 0..3
  const int wq    = w & 1;       // 16-row half within group
  const int lr    = lane & 15;
  const int hi    = lane >> 4;
  const int lk    = hi * 8;
  const int rbase = hi * 4;

  bf16x8 qa[4];
  {
    const long qrow = (base + q0 + wq * 16 + lr) * (long)DKEY;
#pragma unroll
    for (int dk = 0; dk < 4; ++dk)
      qa[dk] = *reinterpret_cast<const bf16x8*>(&Q[qrow + dk * 32 + lk]);
  }

  const f32x4 zero = {0.f, 0.f, 0.f, 0.f};
  f32x4 oacc[8];
#pragma unroll
  for (int n = 0; n < 8; ++n) oacc[n] = zero;
  float m_run[4], l_run[4];
#pragma unroll
  for (int r = 0; r < 4; ++r) { m_run[r] = -1e30f; l_run[r] = 0.0f; }

  const float sc = 0.08838834764831845f;  // 1/sqrt(128)
  const unsigned short* VtB = Vt + (size_t)b * DKEY * SEQ;

  for (int st = 0; st < nsteps; ++st) {
    const int kt  = st * 4 + g;
    const bool act = kt < nt;
    const int kv0 = kt * 64;

    if (act) {
      const unsigned short* Kp = K + (base + kv0) * (long)DKEY;
#pragma unroll
      for (int it = 0; it < 8; ++it) {
        int c = it * 128 + wq * 64 + lane;
        int row = c >> 4, sl = (c & 15) ^ (row & 7);
        *reinterpret_cast<u16x8*>(&Kl[g][row][sl * 8]) =
            *reinterpret_cast<const u16x8*>(&Kp[(size_t)c * 8]);
      }
#pragma unroll
      for (int it = 0; it < 8; ++it) {
        int c = it * 128 + wq * 64 + lane;
        int d = c >> 3, sl = c & 7, slp = sl ^ (d & 7);
        *reinterpret_cast<u16x8*>(&Vl[g][d][slp * 8]) =
            *reinterpret_cast<const u16x8*>(&VtB[(size_t)d * SEQ + kv0 + sl * 8]);
      }
    }
    __syncthreads();

    if (act) {
      f32x4 s[4];
#pragma unroll
      for (int kc = 0; kc < 4; ++kc) {
        s[kc] = zero;
#pragma unroll
        for (int dk = 0; dk < 4; ++dk) {
          bf16x8 kb = *reinterpret_cast<const bf16x8*>(
              &Kl[g][kc * 16 + lr][((dk * 4 + hi) ^ (lr & 7)) * 8]);
          s[kc] = __builtin_amdgcn_mfma_f32_16x16x32_bf16(qa[dk], kb, s[kc], 0, 0, 0);
        }
      }

      const bool dmask = (kt == nt - 1);
      float x[4][4];
#pragma unroll
      for (int kc = 0; kc < 4; ++kc)
#pragma unroll
        for (int r = 0; r < 4; ++r) {
          float xv = s[kc][r] * sc;
          if (dmask) {
            int col  = kv0 + kc * 16 + lr;
            int rowq = q0 + wq * 16 + rbase + r;
            if (col > rowq) xv = -1e30f;
          }
          x[kc][r] = xv;
        }

#pragma unroll
      for (int r = 0; r < 4; ++r) {
        float tm = fmaxf(fmaxf(x[0][r], x[1][r]), fmaxf(x[2][r], x[3][r]));
        tm = fmaxf(tm, __shfl_xor(tm, 1));
        tm = fmaxf(tm, __shfl_xor(tm, 2));
        tm = fmaxf(tm, __shfl_xor(tm, 4));
        tm = fmaxf(tm, __shfl_xor(tm, 8));
        float mnew = fmaxf(m_run[r], tm);
        float scl  = __expf(m_run[r] - mnew);
        m_run[r] = mnew;
        float ps = 0.0f;
#pragma unroll
        for (int kc = 0; kc < 4; ++kc) {
          float pp = __expf(x[kc][r] - mnew);
          ps += pp;
          Plds[w][rbase + r][kc * 16 + lr] = f2bf(pp);
        }
        ps += __shfl_xor(ps, 1);
        ps += __shfl_xor(ps, 2);
        ps += __shfl_xor(ps, 4);
        ps += __shfl_xor(ps, 8);
        l_run[r] = l_run[r] * scl + ps;
#pragma unroll
        for (int n = 0; n < 8; ++n) oacc[n][r] *= scl;
      }

#pragma unroll
      for (int kk = 0; kk < 2; ++kk) {
        bf16x8 pa = *reinterpret_cast<const bf16x8*>(&Plds[w][lr][kk * 32 + lk]);
#pragma unroll
        for (int n = 0; n < 8; ++n) {
          bf16x8 vb = *reinterpret_cast<const bf16x8*>(
              &Vl[g][n * 16 + lr][((kk * 4 + hi) ^ (lr & 7)) * 8]);
          oacc[n] = __builtin_amdgcn_mfma_f32_16x16x32_bf16(pa, vb, oacc[n], 0, 0, 0);
        }
      }
    }
    __syncthreads();
  }

  float* Om = reinterpret_cast<float*>(&Kl[0][0][0]);   // [4][32][128] alias
#pragma unroll
  for (int n = 0; n < 8; ++n)
#pragma unroll
    for (int r = 0; r < 4; ++r)
      Om[(g * 32 + wq * 16 + rbase + r) * 128 + n * 16 + lr] = oacc[n][r];
  if (lr == 0) {
#pragma unroll
    for (int r = 0; r < 4; ++r) {
      Sm[g][wq * 16 + rbase + r] = m_run[r];
      Sl[g][wq * 16 + rbase + r] = l_run[r];
    }
  }
  __syncthreads();

  const int row = t >> 4;          // 0..31
  const int c0  = (t & 15) * 8;    // 0..120
  float mM = fmaxf(fmaxf(Sm[0][row], Sm[1][row]), fmaxf(Sm[2][row], Sm[3][row]));
  float wts[4], lsum = 0.0f;
#pragma unroll
  for (int gv = 0; gv < 4; ++gv) {
    wts[gv] = __expf(Sm[gv][row] - mM);
    lsum += wts[gv] * Sl[gv][row];
  }
  const float linv = 1.0f / lsum;
  f32x4 o0 = zero, o1 = zero;
#pragma unroll
  for (int gv = 0; gv < 4; ++gv) {
    const float* src = &Om[(gv * 32 + row) * 128 + c0];
    f32x4 a0 = *reinterpret_cast<const f32x4*>(src);
    f32x4 a1 = *reinterpret_cast<const f32x4*>(src + 4);
    const float wt = wts[gv];
#pragma unroll
    for (int j = 0; j < 4; ++j) { o0[j] += wt * a0[j]; o1[j] += wt * a1[j]; }
  }
#pragma unroll
  for (int j = 0; j < 4; ++j) { o0[j] *= linv; o1[j] *= linv; }
  float* op = &O[(base + q0 + row) * (long)DKEY + c0];
  *reinterpret_cast<f32x4*>(op)     = o0;
  *reinterpret_cast<f32x4*>(op + 4) = o1;
}

extern "C" void kernel_launch(void* const* d_in, const int* in_sizes, int n_in,
                              void* d_out, int out_size, void* d_ws, size_t ws_size,
                              hipStream_t stream) {
  const float* Xq = (const float*)d_in[0];
  const float* Xk = (const float*)d_in[1];
  const float* Xv = (const float*)d_in[2];
  // d_in[3] = mask: tril by construction; causality handled analytically.
  const float* Wq = (const float*)d_in[4];
  const float* Wk = (const float*)d_in[5];
  const float* Wv = (const float*)d_in[6];

  // ws layout: Q (2MB), K (2MB), V^T (2MB) bf16. ws >= 6MB (round-1 evidence).
  unsigned short* qp  = (unsigned short*)d_ws;
  unsigned short* kp  = qp + (size_t)NB * SEQ * DKEY;
  unsigned short* vtp = kp + (size_t)NB * SEQ * DKEY;
  // W-bf16 (0.75MB) lives in d_out: written by wconv, read only by proj,
  // then fully overwritten by attn's O-stores (stream-ordered => safe,
  // deterministic across graph replays).
  unsigned short* wbp = (unsigned short*)d_out;

  hipLaunchKernelGGL(wconv_kernel, dim3(192), dim3(256), 0, stream,
                     Wq, Wk, Wv, wbp);
  dim3 g1(SEQ * NB / 64, 1, 3);   // 128 x 3
  hipLaunchKernelGGL(proj_kernel, g1, dim3(256), 0, stream,
                     Xq, Xk, Xv, wbp, qp, kp, vtp);
  hipLaunchKernelGGL(attn_kernel, dim3(256), dim3(512), 0, stream,
                     qp, kp, vtp, (float*)d_out);
}